// Round 6
// baseline (219.944 us; speedup 1.0000x reference)
//
#include <hip/hip_runtime.h>

#define TT 512   // timesteps
#define ID 32    // input features
#define HD 64    // hidden
#define NTK 8    // tickers
#define RPB 16   // batch rows per block (= MFMA N)

typedef __attribute__((ext_vector_type(8))) _Float16 half8;
typedef __attribute__((ext_vector_type(4))) float f32x4;

__device__ __forceinline__ float rcp1p(float e) {   // 1/(1+e)
    return __builtin_amdgcn_rcpf(1.0f + e);
}

// Pre-pass: x f32 -> f16 (one half8 per thread)
__global__ void cvt_x(const float* __restrict__ x, _Float16* __restrict__ xo, int n8) {
    int i = blockIdx.x * blockDim.x + threadIdx.x;
    if (i >= n8) return;
    const float4* p = (const float4*)x + 2 * (size_t)i;
    float4 a = p[0], b = p[1];
    half8 o = {(_Float16)a.x, (_Float16)a.y, (_Float16)a.z, (_Float16)a.w,
               (_Float16)b.x, (_Float16)b.y, (_Float16)b.z, (_Float16)b.w};
    *((half8*)xo + i) = o;
}

// TRANSPOSED formulation: C(gates x rows) = W_z(256x96) @ z^T(96x16).
// 32 blocks x 512 threads (8 waves); each block owns 16 batch rows.
// Gate rows PERMUTED: row 4u+g = gate g of hidden unit u, pre-scaled by
// s_g (-log2e sigmoid, +2log2e tanh) -> activation = rcp(1+exp2(acc)) affine.
// A = permuted/scaled W (loop-invariant registers); B = z fragments:
// col n = lane&15 = batch row, k = (lane>>4)*8+j. C: row m=(lane>>4)*4+reg
// = permuted gate row -> reg r is gate r (i,f,g,o) of unit mt*4+lq for
// batch row lane&15: activation + c-state fully lane-local, no shfl.
template <bool XF16>
__global__ __launch_bounds__(512, 1) void lstm_T(
    const float* __restrict__ x,       // (B, T, I) f32 (fallback)
    const _Float16* __restrict__ xf,   // (B, T, I) f16 (fast path)
    const float* __restrict__ w_ih,    // (4H, I)
    const float* __restrict__ w_hh,    // (4H, H)
    const float* __restrict__ b_ih,    // (4H)
    const float* __restrict__ b_hh,    // (4H)
    const float* __restrict__ w_fc,    // (NTK, H)
    const float* __restrict__ b_fc,    // (NTK)
    float* __restrict__ out)           // (B, NTK)
{
    const int tid = threadIdx.x;
    const int wv  = tid >> 6;          // wave 0..7: owns M-tiles {2wv, 2wv+1}
    const int l   = tid & 63;
    const int l15 = l & 15;            // = batch row (B/C col) & A gate-row
    const int lq  = l >> 4;            // k-chunk / C row-quad selector
    const int r0  = blockIdx.x * RPB;

    // h state, double-buffered; rows padded to 68 f16 (136 B) for bank spread
    __shared__ __align__(16) _Float16 zbuf[2][RPB][68];

    constexpr float L2E = 1.44269504089f;

    // ---- loop-invariant A fragments (permuted, scaled, f16) + bias C-in ----
    half8 Ax[2], Ah0[2], Ah1[2];
    f32x4 biasC[2];
    #pragma unroll
    for (int nt = 0; nt < 2; ++nt) {
        const int mt = 2 * wv + nt;                 // M-tile 0..15
        const int g  = l15 & 3;                     // gate of this A row
        const int u  = mt * 4 + (l15 >> 2);         // hidden unit of this A row
        const int orig = g * HD + u;                // original W row
        const float s = (g == 2) ? 2.0f * L2E : -L2E;
        const float* ph = w_hh + orig * HD + lq * 8;
        const float* px = w_ih + orig * ID + lq * 8;
        float4 p0, p1;
        p0 = ((const float4*)ph)[0]; p1 = ((const float4*)ph)[1];
        Ah0[nt] = (half8){(_Float16)(s*p0.x), (_Float16)(s*p0.y), (_Float16)(s*p0.z), (_Float16)(s*p0.w),
                          (_Float16)(s*p1.x), (_Float16)(s*p1.y), (_Float16)(s*p1.z), (_Float16)(s*p1.w)};
        p0 = ((const float4*)(ph + 32))[0]; p1 = ((const float4*)(ph + 32))[1];
        Ah1[nt] = (half8){(_Float16)(s*p0.x), (_Float16)(s*p0.y), (_Float16)(s*p0.z), (_Float16)(s*p0.w),
                          (_Float16)(s*p1.x), (_Float16)(s*p1.y), (_Float16)(s*p1.z), (_Float16)(s*p1.w)};
        p0 = ((const float4*)px)[0]; p1 = ((const float4*)px)[1];
        Ax[nt]  = (half8){(_Float16)(s*p0.x), (_Float16)(s*p0.y), (_Float16)(s*p0.z), (_Float16)(s*p0.w),
                          (_Float16)(s*p1.x), (_Float16)(s*p1.y), (_Float16)(s*p1.z), (_Float16)(s*p1.w)};
        #pragma unroll
        for (int r = 0; r < 4; ++r) {               // C reg r = gate r of unit mt*4+lq
            const int orig_r = r * HD + mt * 4 + lq;
            const float sr = (r == 2) ? 2.0f * L2E : -L2E;
            biasC[nt][r] = sr * (b_ih[orig_r] + b_hh[orig_r]);
        }
    }

    // zbuf[0] = h(0) = 0  (512 threads x 2 writes cover 16x64)
    {
        const int n = tid >> 5, j = tid & 31;
        zbuf[0][n][j] = (_Float16)0.0f;
        zbuf[0][n][32 + j] = (_Float16)0.0f;
    }

    // x B-fragment pointers: lane supplies col l15 (its batch row), k-chunk lq
    const _Float16* xp = xf + ((size_t)(r0 + l15) * TT) * ID + lq * 8;
    const float*    xq = x  + ((size_t)(r0 + l15) * TT) * ID + lq * 8;

    auto ldx = [&]() -> half8 {
        if constexpr (XF16) {
            return *(const half8*)xp;
        } else {
            float4 a = ((const float4*)xq)[0], b = ((const float4*)xq)[1];
            return (half8){(_Float16)a.x, (_Float16)a.y, (_Float16)a.z, (_Float16)a.w,
                           (_Float16)b.x, (_Float16)b.y, (_Float16)b.z, (_Float16)b.w};
        }
    };

    half8 xa = ldx();                   // t = 0
    float c0 = 0.0f, c1 = 0.0f;

    auto step = [&](int rbuf, int wbuf, half8 xc) {
        half8 z0 = *(const half8*)&zbuf[rbuf][l15][lq * 8];        // h[k 0..31]
        half8 z1 = *(const half8*)&zbuf[rbuf][l15][32 + lq * 8];   // h[k 32..63]

        // x-part first (no LDS dependency; issues under ds_read latency)
        f32x4 a0 = __builtin_amdgcn_mfma_f32_16x16x32_f16(Ax[0], xc, biasC[0], 0, 0, 0);
        f32x4 a1 = __builtin_amdgcn_mfma_f32_16x16x32_f16(Ax[1], xc, biasC[1], 0, 0, 0);
        a0 = __builtin_amdgcn_mfma_f32_16x16x32_f16(Ah0[0], z0, a0, 0, 0, 0);
        a1 = __builtin_amdgcn_mfma_f32_16x16x32_f16(Ah0[1], z0, a1, 0, 0, 0);
        a0 = __builtin_amdgcn_mfma_f32_16x16x32_f16(Ah1[0], z1, a0, 0, 0, 0);
        a1 = __builtin_amdgcn_mfma_f32_16x16x32_f16(Ah1[1], z1, a1, 0, 0, 0);

        // unit u = 8wv+lq (tile 0) : regs are i,f,g,o pre-acts (scaled)
        {
            const float ei = rcp1p(__builtin_amdgcn_exp2f(a0[0]));
            const float ef = rcp1p(__builtin_amdgcn_exp2f(a0[1]));
            const float eg = rcp1p(__builtin_amdgcn_exp2f(a0[2]));
            const float eo = rcp1p(__builtin_amdgcn_exp2f(a0[3]));
            const float gg = fmaf(-2.0f, eg, 1.0f);
            c0 = fmaf(ef, c0, ei * gg);
            const float th = fmaf(-2.0f, rcp1p(__builtin_amdgcn_exp2f(2.88539008178f * c0)), 1.0f);
            zbuf[wbuf][l15][8 * wv + lq] = (_Float16)(eo * th);
        }
        // unit u = 8wv+4+lq (tile 1)
        {
            const float ei = rcp1p(__builtin_amdgcn_exp2f(a1[0]));
            const float ef = rcp1p(__builtin_amdgcn_exp2f(a1[1]));
            const float eg = rcp1p(__builtin_amdgcn_exp2f(a1[2]));
            const float eo = rcp1p(__builtin_amdgcn_exp2f(a1[3]));
            const float gg = fmaf(-2.0f, eg, 1.0f);
            c1 = fmaf(ef, c1, ei * gg);
            const float th = fmaf(-2.0f, rcp1p(__builtin_amdgcn_exp2f(2.88539008178f * c1)), 1.0f);
            zbuf[wbuf][l15][8 * wv + 4 + lq] = (_Float16)(eo * th);
        }
    };

    __syncthreads();

    for (int t = 0; t < TT; t += 2) {
        half8 x0 = xa;
        xp += ID; xq += ID;             // t+1 (t <= 510, always valid)
        xa = ldx();
        step(0, 1, x0);
        __syncthreads();

        half8 x1 = xa;
        if (t + 2 < TT) { xp += ID; xq += ID; }
        xa = ldx();
        step(1, 0, x1);
        __syncthreads();
    }

    // h(T) is in zbuf[0]. FC head: 128 threads, one (row, ticker) each.
    if (tid < RPB * NTK) {
        const int n  = tid >> 3;
        const int tk = tid & 7;
        float a = b_fc[tk];
        const float* wf = w_fc + tk * HD;
        #pragma unroll
        for (int j = 0; j < HD; ++j)
            a = fmaf((float)zbuf[0][n][j], wf[j], a);
        out[(r0 + n) * NTK + tk] = a;
    }
}

extern "C" void kernel_launch(void* const* d_in, const int* in_sizes, int n_in,
                              void* d_out, int out_size, void* d_ws, size_t ws_size,
                              hipStream_t stream) {
    const float* x    = (const float*)d_in[0];
    const float* w_ih = (const float*)d_in[1];
    const float* w_hh = (const float*)d_in[2];
    const float* b_ih = (const float*)d_in[3];
    const float* b_hh = (const float*)d_in[4];
    const float* w_fc = (const float*)d_in[5];
    const float* b_fc = (const float*)d_in[6];
    float* out = (float*)d_out;

    const int nx = in_sizes[0];              // B*T*I
    const int B  = nx / (TT * ID);           // 512
    const size_t need = (size_t)nx * sizeof(_Float16);

    if (ws_size >= need) {
        _Float16* xf = (_Float16*)d_ws;
        const int n8 = nx / 8;
        cvt_x<<<dim3((n8 + 255) / 256), dim3(256), 0, stream>>>(x, xf, n8);
        lstm_T<true><<<dim3(B / RPB), dim3(512), 0, stream>>>(x, xf, w_ih, w_hh,
                                                              b_ih, b_hh, w_fc, b_fc, out);
    } else {
        lstm_T<false><<<dim3(B / RPB), dim3(512), 0, stream>>>(x, (const _Float16*)d_ws,
                                                               w_ih, w_hh, b_ih, b_hh,
                                                               w_fc, b_fc, out);
    }
}

// Round 7
// 153.730 us; speedup vs baseline: 1.4307x; 1.4307x over previous
//
#include <hip/hip_runtime.h>

#define TT 512   // timesteps
#define ID 32    // input features
#define HD 64    // hidden
#define NTK 8    // tickers
#define RPB 4    // batch rows per block
#define ZPAD 80  // f16 elems per zbuf row (conflict-free h writeback)

typedef __attribute__((ext_vector_type(8))) _Float16 half8;
typedef __attribute__((ext_vector_type(4))) float f32x4;

__device__ __forceinline__ float sigm(float v) {
    return __builtin_amdgcn_rcpf(1.0f + __builtin_amdgcn_exp2f(-1.44269504089f * v));
}
__device__ __forceinline__ float tanhfast(float v) {
    return fmaf(-2.0f, __builtin_amdgcn_rcpf(1.0f + __builtin_amdgcn_exp2f(2.88539008178f * v)), 1.0f);
}

// Pre-pass: x f32 -> f16 (one half8 per thread)
__global__ void cvt_x(const float* __restrict__ x, _Float16* __restrict__ xo, int n8) {
    int i = blockIdx.x * blockDim.x + threadIdx.x;
    if (i >= n8) return;
    const float4* p = (const float4*)x + 2 * (size_t)i;
    float4 a = p[0], b = p[1];
    half8 o = {(_Float16)a.x, (_Float16)a.y, (_Float16)a.z, (_Float16)a.w,
               (_Float16)b.x, (_Float16)b.y, (_Float16)b.z, (_Float16)b.w};
    *((half8*)xo + i) = o;
}

// 128 blocks x 256 threads (4 waves), 4 batch rows per block.
// gates(4 rows x 256) = z(4x96, rows 4x-duplicated to M=16) @ W^T via
// mfma_f32_16x16x32_f16. A row m = batch row m>>2; C row m=lq*4+r -> batch lq,
// so lane (lq,l15) of wave wv activates the unique gate quad
// (i,f,g,o) = acc[0..3][0] of (batch row lq, hidden unit 16wv+l15).
// Chain shorteners vs R4: depth-2 x prefetch (slack > HBM latency),
// t-unroll-by-2 (static LDS indices), zero activation redundancy.
template <bool XF16>
__global__ __launch_bounds__(256, 2) void lstm4(
    const float* __restrict__ x,       // (B, T, I) f32 (fallback)
    const _Float16* __restrict__ xf,   // (B, T, I) f16 (fast path)
    const float* __restrict__ w_ih,    // (4H, I)
    const float* __restrict__ w_hh,    // (4H, H)
    const float* __restrict__ b_ih,    // (4H)
    const float* __restrict__ b_hh,    // (4H)
    const float* __restrict__ w_fc,    // (NTK, H)
    const float* __restrict__ b_fc,    // (NTK)
    float* __restrict__ out)           // (B, NTK)
{
    const int tid = threadIdx.x;
    const int wv  = tid >> 6;          // wave 0..3: owns gate cols 16wv.. in each gate block
    const int l   = tid & 63;
    const int l15 = l & 15;
    const int lq  = l >> 4;            // k-chunk for A/B; = batch row this lane activates
    const int abr = l15 >> 2;          // batch row this lane's A-row supplies
    const int r0  = blockIdx.x * RPB;

    __shared__ __align__(16) _Float16 zbuf[2][RPB][ZPAD];   // double-buffered h

    // ---- loop-invariant B fragments (W^T) + bias C-in ----
    // B layout: col n = lane&15, k = (lane>>4)*8 + j.
    half8 Bh0[4], Bh1[4], Bx[4];
    f32x4 biasC[4];
    #pragma unroll
    for (int nt = 0; nt < 4; ++nt) {
        const int n = nt * 64 + wv * 16 + l15;   // gate index (block nt = gate type)
        const float bias = b_ih[n] + b_hh[n];
        biasC[nt] = (f32x4){bias, bias, bias, bias};
        const float* ph = w_hh + n * HD + lq * 8;
        float4 p0 = ((const float4*)ph)[0], p1 = ((const float4*)ph)[1];
        Bh0[nt] = (half8){(_Float16)p0.x, (_Float16)p0.y, (_Float16)p0.z, (_Float16)p0.w,
                          (_Float16)p1.x, (_Float16)p1.y, (_Float16)p1.z, (_Float16)p1.w};
        p0 = ((const float4*)(ph + 32))[0]; p1 = ((const float4*)(ph + 32))[1];
        Bh1[nt] = (half8){(_Float16)p0.x, (_Float16)p0.y, (_Float16)p0.z, (_Float16)p0.w,
                          (_Float16)p1.x, (_Float16)p1.y, (_Float16)p1.z, (_Float16)p1.w};
        const float* px = w_ih + n * ID + lq * 8;
        p0 = ((const float4*)px)[0]; p1 = ((const float4*)px)[1];
        Bx[nt]  = (half8){(_Float16)p0.x, (_Float16)p0.y, (_Float16)p0.z, (_Float16)p0.w,
                          (_Float16)p1.x, (_Float16)p1.y, (_Float16)p1.z, (_Float16)p1.w};
    }

    // zbuf[0] = h(0) = 0: 256 threads cover [4][64] exactly
    zbuf[0][tid >> 6][tid & 63] = (_Float16)0.0f;

    // x loads: lane supplies A-row l15 -> x[r0+abr][t][lq*8 .. +8)
    const size_t xoff = ((size_t)(r0 + abr) * TT) * ID + lq * 8;
    const _Float16* xp = xf + xoff;
    const float*    xq = x  + xoff;

    auto ldx = [&](int tstep) -> half8 {
        if constexpr (XF16) {
            return *(const half8*)(xp + (size_t)tstep * ID);
        } else {
            const float* s = xq + (size_t)tstep * ID;
            float4 a = ((const float4*)s)[0], b = ((const float4*)s)[1];
            return (half8){(_Float16)a.x, (_Float16)a.y, (_Float16)a.z, (_Float16)a.w,
                           (_Float16)b.x, (_Float16)b.y, (_Float16)b.z, (_Float16)b.w};
        }
    };

    half8 xa = ldx(0);      // phase-A register (even t)
    half8 xb = ldx(1);      // phase-B register (odd t)
    float c_ = 0.0f;
    __syncthreads();

#define STEP(RB, WB, XREG)                                                          \
    {                                                                               \
        half8 z0 = *(const half8*)&zbuf[RB][abr][lq * 8];                           \
        half8 z1 = *(const half8*)&zbuf[RB][abr][32 + lq * 8];                      \
        f32x4 a0 = __builtin_amdgcn_mfma_f32_16x16x32_f16(XREG, Bx[0], biasC[0], 0, 0, 0); \
        f32x4 a1 = __builtin_amdgcn_mfma_f32_16x16x32_f16(XREG, Bx[1], biasC[1], 0, 0, 0); \
        f32x4 a2 = __builtin_amdgcn_mfma_f32_16x16x32_f16(XREG, Bx[2], biasC[2], 0, 0, 0); \
        f32x4 a3 = __builtin_amdgcn_mfma_f32_16x16x32_f16(XREG, Bx[3], biasC[3], 0, 0, 0); \
        a0 = __builtin_amdgcn_mfma_f32_16x16x32_f16(z0, Bh0[0], a0, 0, 0, 0);       \
        a1 = __builtin_amdgcn_mfma_f32_16x16x32_f16(z0, Bh0[1], a1, 0, 0, 0);       \
        a2 = __builtin_amdgcn_mfma_f32_16x16x32_f16(z0, Bh0[2], a2, 0, 0, 0);       \
        a3 = __builtin_amdgcn_mfma_f32_16x16x32_f16(z0, Bh0[3], a3, 0, 0, 0);       \
        a0 = __builtin_amdgcn_mfma_f32_16x16x32_f16(z1, Bh1[0], a0, 0, 0, 0);       \
        a1 = __builtin_amdgcn_mfma_f32_16x16x32_f16(z1, Bh1[1], a1, 0, 0, 0);       \
        a2 = __builtin_amdgcn_mfma_f32_16x16x32_f16(z1, Bh1[2], a2, 0, 0, 0);       \
        a3 = __builtin_amdgcn_mfma_f32_16x16x32_f16(z1, Bh1[3], a3, 0, 0, 0);       \
        const float ig = sigm(a0[0]);                                               \
        const float fg = sigm(a1[0]);                                               \
        const float gg = tanhfast(a2[0]);                                           \
        const float og = sigm(a3[0]);                                               \
        c_ = fmaf(fg, c_, ig * gg);                                                 \
        const float hh = og * tanhfast(c_);                                         \
        zbuf[WB][lq][wv * 16 + l15] = (_Float16)hh;                                 \
    }

    for (int t = 0; t < TT; t += 2) {
        {   // phase A: even step, read buf0 -> write buf1
            half8 xcur = xa;
            if (t + 2 < TT) xa = ldx(t + 2);    // depth-2 prefetch
            STEP(0, 1, xcur);
        }
        __syncthreads();
        {   // phase B: odd step, read buf1 -> write buf0
            half8 xcur = xb;
            if (t + 3 < TT) xb = ldx(t + 3);
            STEP(1, 0, xcur);
        }
        __syncthreads();
    }
#undef STEP

    // h(T) in zbuf[0]. FC head: 32 threads, one (row, ticker) each.
    if (tid < RPB * NTK) {
        const int rr = tid >> 3;
        const int tk = tid & 7;
        float a = b_fc[tk];
        const float* wf = w_fc + tk * HD;
        #pragma unroll
        for (int j = 0; j < HD; ++j)
            a = fmaf((float)zbuf[0][rr][j], wf[j], a);
        out[(r0 + rr) * NTK + tk] = a;
    }
}

extern "C" void kernel_launch(void* const* d_in, const int* in_sizes, int n_in,
                              void* d_out, int out_size, void* d_ws, size_t ws_size,
                              hipStream_t stream) {
    const float* x    = (const float*)d_in[0];
    const float* w_ih = (const float*)d_in[1];
    const float* w_hh = (const float*)d_in[2];
    const float* b_ih = (const float*)d_in[3];
    const float* b_hh = (const float*)d_in[4];
    const float* w_fc = (const float*)d_in[5];
    const float* b_fc = (const float*)d_in[6];
    float* out = (float*)d_out;

    const int nx = in_sizes[0];              // B*T*I
    const int B  = nx / (TT * ID);           // 512
    const size_t need = (size_t)nx * sizeof(_Float16);

    if (ws_size >= need) {
        _Float16* xf = (_Float16*)d_ws;
        const int n8 = nx / 8;
        cvt_x<<<dim3((n8 + 255) / 256), dim3(256), 0, stream>>>(x, xf, n8);
        lstm4<true><<<dim3(B / RPB), dim3(256), 0, stream>>>(x, xf, w_ih, w_hh,
                                                             b_ih, b_hh, w_fc, b_fc, out);
    } else {
        lstm4<false><<<dim3(B / RPB), dim3(256), 0, stream>>>(x, (const _Float16*)d_ws,
                                                              w_ih, w_hh, b_ih, b_hh,
                                                              w_fc, b_fc, out);
    }
}

// Round 8
// 150.025 us; speedup vs baseline: 1.4660x; 1.0247x over previous
//
#include <hip/hip_runtime.h>

#define TT 512   // timesteps
#define ID 32    // input features
#define HD 64    // hidden
#define NTK 8    // tickers
#define RPB 4    // batch rows per block
#define ZPAD 80  // f16 elems per zbuf row (conflict-free h writeback)

typedef __attribute__((ext_vector_type(8))) _Float16 half8;
typedef __attribute__((ext_vector_type(4))) float f32x4;

#define L2E 1.44269504089f

// Pre-pass: x f32 -> f16 (one half8 per thread)
__global__ void cvt_x(const float* __restrict__ x, _Float16* __restrict__ xo, int n8) {
    int i = blockIdx.x * blockDim.x + threadIdx.x;
    if (i >= n8) return;
    const float4* p = (const float4*)x + 2 * (size_t)i;
    float4 a = p[0], b = p[1];
    half8 o = {(_Float16)a.x, (_Float16)a.y, (_Float16)a.z, (_Float16)a.w,
               (_Float16)b.x, (_Float16)b.y, (_Float16)b.z, (_Float16)b.w};
    *((half8*)xo + i) = o;
}

// 128 blocks x 256 threads (4 waves), 4 batch rows per block (R7 skeleton).
// Fused activations: sig(i)*tanh(g) = (eg-1)/((1+ei)(1+eg)),
// sig(o)*tanh(c)   = (ec-1)/((1+eo)(1+ec))  -> 5 exp2 + 3 rcp per lane
// (was 5+5). exp2 args clamped at 60 so fused denominators never overflow;
// carried c state stays exact.
template <bool XF16>
__global__ __launch_bounds__(256, 2) void lstm4(
    const float* __restrict__ x,       // (B, T, I) f32 (fallback)
    const _Float16* __restrict__ xf,   // (B, T, I) f16 (fast path)
    const float* __restrict__ w_ih,    // (4H, I)
    const float* __restrict__ w_hh,    // (4H, H)
    const float* __restrict__ b_ih,    // (4H)
    const float* __restrict__ b_hh,    // (4H)
    const float* __restrict__ w_fc,    // (NTK, H)
    const float* __restrict__ b_fc,    // (NTK)
    float* __restrict__ out)           // (B, NTK)
{
    const int tid = threadIdx.x;
    const int wv  = tid >> 6;          // wave 0..3
    const int l   = tid & 63;
    const int l15 = l & 15;
    const int lq  = l >> 4;            // k-chunk; = batch row this lane activates
    const int abr = l15 >> 2;          // batch row this lane's A-row supplies
    const int r0  = blockIdx.x * RPB;

    __shared__ __align__(16) _Float16 zbuf[2][RPB][ZPAD];   // double-buffered h

    // ---- loop-invariant B fragments (W^T) + bias C-in ----
    // B layout: col n = lane&15, k = (lane>>4)*8 + j. nt = gate type (i,f,g,o).
    half8 Bh0[4], Bh1[4], Bx[4];
    f32x4 biasC[4];
    #pragma unroll
    for (int nt = 0; nt < 4; ++nt) {
        const int n = nt * 64 + wv * 16 + l15;
        const float bias = b_ih[n] + b_hh[n];
        biasC[nt] = (f32x4){bias, bias, bias, bias};
        const float* ph = w_hh + n * HD + lq * 8;
        float4 p0 = ((const float4*)ph)[0], p1 = ((const float4*)ph)[1];
        Bh0[nt] = (half8){(_Float16)p0.x, (_Float16)p0.y, (_Float16)p0.z, (_Float16)p0.w,
                          (_Float16)p1.x, (_Float16)p1.y, (_Float16)p1.z, (_Float16)p1.w};
        p0 = ((const float4*)(ph + 32))[0]; p1 = ((const float4*)(ph + 32))[1];
        Bh1[nt] = (half8){(_Float16)p0.x, (_Float16)p0.y, (_Float16)p0.z, (_Float16)p0.w,
                          (_Float16)p1.x, (_Float16)p1.y, (_Float16)p1.z, (_Float16)p1.w};
        const float* px = w_ih + n * ID + lq * 8;
        p0 = ((const float4*)px)[0]; p1 = ((const float4*)px)[1];
        Bx[nt]  = (half8){(_Float16)p0.x, (_Float16)p0.y, (_Float16)p0.z, (_Float16)p0.w,
                          (_Float16)p1.x, (_Float16)p1.y, (_Float16)p1.z, (_Float16)p1.w};
    }

    zbuf[0][tid >> 6][tid & 63] = (_Float16)0.0f;   // h(0) = 0

    const size_t xoff = ((size_t)(r0 + abr) * TT) * ID + lq * 8;
    const _Float16* xp = xf + xoff;
    const float*    xq = x  + xoff;

    auto ldx = [&](int tstep) -> half8 {
        if constexpr (XF16) {
            return *(const half8*)(xp + (size_t)tstep * ID);
        } else {
            const float* s = xq + (size_t)tstep * ID;
            float4 a = ((const float4*)s)[0], b = ((const float4*)s)[1];
            return (half8){(_Float16)a.x, (_Float16)a.y, (_Float16)a.z, (_Float16)a.w,
                           (_Float16)b.x, (_Float16)b.y, (_Float16)b.z, (_Float16)b.w};
        }
    };

    half8 xa = ldx(0);      // even-t register
    half8 xb = ldx(1);      // odd-t register
    float c_ = 0.0f;
    __syncthreads();

    // Gate streams: aI,aF,aG,aO (i,f,g,o). o is needed latest in the act tail.
#define STEP(RB, WB, XREG)                                                          \
    {                                                                               \
        half8 z0 = *(const half8*)&zbuf[RB][abr][lq * 8];                           \
        half8 z1 = *(const half8*)&zbuf[RB][abr][32 + lq * 8];                      \
        f32x4 aF = __builtin_amdgcn_mfma_f32_16x16x32_f16(XREG, Bx[1], biasC[1], 0, 0, 0); \
        f32x4 aI = __builtin_amdgcn_mfma_f32_16x16x32_f16(XREG, Bx[0], biasC[0], 0, 0, 0); \
        f32x4 aG = __builtin_amdgcn_mfma_f32_16x16x32_f16(XREG, Bx[2], biasC[2], 0, 0, 0); \
        f32x4 aO = __builtin_amdgcn_mfma_f32_16x16x32_f16(XREG, Bx[3], biasC[3], 0, 0, 0); \
        aF = __builtin_amdgcn_mfma_f32_16x16x32_f16(z0, Bh0[1], aF, 0, 0, 0);       \
        aI = __builtin_amdgcn_mfma_f32_16x16x32_f16(z0, Bh0[0], aI, 0, 0, 0);       \
        aG = __builtin_amdgcn_mfma_f32_16x16x32_f16(z0, Bh0[2], aG, 0, 0, 0);       \
        aO = __builtin_amdgcn_mfma_f32_16x16x32_f16(z0, Bh0[3], aO, 0, 0, 0);       \
        aF = __builtin_amdgcn_mfma_f32_16x16x32_f16(z1, Bh1[1], aF, 0, 0, 0);       \
        aI = __builtin_amdgcn_mfma_f32_16x16x32_f16(z1, Bh1[0], aI, 0, 0, 0);       \
        aG = __builtin_amdgcn_mfma_f32_16x16x32_f16(z1, Bh1[2], aG, 0, 0, 0);       \
        aO = __builtin_amdgcn_mfma_f32_16x16x32_f16(z1, Bh1[3], aO, 0, 0, 0);       \
        const float ef = __builtin_amdgcn_exp2f(-L2E * aF[0]);                      \
        const float ei = __builtin_amdgcn_exp2f(-L2E * aI[0]);                      \
        const float eg = __builtin_amdgcn_exp2f(fminf(2.0f * L2E * aG[0], 60.0f));  \
        const float eo = __builtin_amdgcn_exp2f(-L2E * aO[0]);                      \
        const float rf  = __builtin_amdgcn_rcpf(1.0f + ef);                         \
        const float ti  = 1.0f + ei;                                                \
        const float rig = __builtin_amdgcn_rcpf(fmaf(eg, ti, ti));                  \
        c_ = fmaf(c_, rf, fmaf(eg, rig, -rig));                                     \
        const float ec = __builtin_amdgcn_exp2f(fminf(2.0f * L2E * c_, 60.0f));     \
        const float to = 1.0f + eo;                                                 \
        const float rh = __builtin_amdgcn_rcpf(fmaf(ec, to, to));                   \
        const float hh = fmaf(ec, rh, -rh);                                         \
        zbuf[WB][lq][wv * 16 + l15] = (_Float16)hh;                                 \
    }

    for (int t = 0; t < TT; t += 2) {
        {   // phase A: read buf0 -> write buf1
            half8 xcur = xa;
            if (t + 2 < TT) xa = ldx(t + 2);    // depth-2 prefetch
            STEP(0, 1, xcur);
        }
        __syncthreads();
        {   // phase B: read buf1 -> write buf0
            half8 xcur = xb;
            if (t + 3 < TT) xb = ldx(t + 3);
            STEP(1, 0, xcur);
        }
        __syncthreads();
    }
#undef STEP

    // h(T) in zbuf[0]. FC head: 32 threads, one (row, ticker) each.
    if (tid < RPB * NTK) {
        const int rr = tid >> 3;
        const int tk = tid & 7;
        float a = b_fc[tk];
        const float* wf = w_fc + tk * HD;
        #pragma unroll
        for (int j = 0; j < HD; ++j)
            a = fmaf((float)zbuf[0][rr][j], wf[j], a);
        out[(r0 + rr) * NTK + tk] = a;
    }
}

extern "C" void kernel_launch(void* const* d_in, const int* in_sizes, int n_in,
                              void* d_out, int out_size, void* d_ws, size_t ws_size,
                              hipStream_t stream) {
    const float* x    = (const float*)d_in[0];
    const float* w_ih = (const float*)d_in[1];
    const float* w_hh = (const float*)d_in[2];
    const float* b_ih = (const float*)d_in[3];
    const float* b_hh = (const float*)d_in[4];
    const float* w_fc = (const float*)d_in[5];
    const float* b_fc = (const float*)d_in[6];
    float* out = (float*)d_out;

    const int nx = in_sizes[0];              // B*T*I
    const int B  = nx / (TT * ID);           // 512
    const size_t need = (size_t)nx * sizeof(_Float16);

    if (ws_size >= need) {
        _Float16* xf = (_Float16*)d_ws;
        const int n8 = nx / 8;
        cvt_x<<<dim3((n8 + 255) / 256), dim3(256), 0, stream>>>(x, xf, n8);
        lstm4<true><<<dim3(B / RPB), dim3(256), 0, stream>>>(x, xf, w_ih, w_hh,
                                                             b_ih, b_hh, w_fc, b_fc, out);
    } else {
        lstm4<false><<<dim3(B / RPB), dim3(256), 0, stream>>>(x, (const _Float16*)d_ws,
                                                              w_ih, w_hh, b_ih, b_hh,
                                                              w_fc, b_fc, out);
    }
}